// Round 6
// baseline (95.506 us; speedup 1.0000x reference)
//
#include <hip/hip_runtime.h>
#include <hip/hip_bf16.h>

// out[b,u] = exp(-0.5 * (|x_b|^2 - 2*x.mu + |mu_u|^2))
// x: (65536, 64) f32; mu: (64, 256) f32; out: (65536, 256) f32.
// bf16 MFMA cross term; |x|^2 / |mu|^2 in fp32 from originals.
// Round-6 change vs round 4 (88.2us): TRANSPOSED MFMA (swap operands,
// T12-style). Lane then holds out[b0+l15][t*16+4g+r], r=0..3 ->
// one dwordx4 store per t (4/tile vs 16 scalar), and the per-tile 4-shfl
// xsq broadcast vanishes (lane's own row norm is already local after the
// xor reduce). mu-norm remap done once in setup (16 shfls).
// Keeps: grid 1024 x 4 tiles, 2-deep pipelined x loads, plain (non-NT) ops.

typedef __attribute__((ext_vector_type(8))) short short8;   // 8 bf16 (4 VGPRs)
typedef __attribute__((ext_vector_type(4))) float floatx4;  // MFMA C/D frag

#define GRIDB 1024
#define TILES 4   // 1024 * 4 * 16 rows = 65536

__device__ inline short f2bf_rne(float f) {
    unsigned int u = __float_as_uint(f);
    u += 0x7fffu + ((u >> 16) & 1u);   // round-to-nearest-even (no NaN in data)
    return (short)(u >> 16);
}

__global__ __launch_bounds__(256, 4) void rbf_kernel(
    const float* __restrict__ x, const float* __restrict__ mu,
    float* __restrict__ out)
{
    const int tid  = threadIdx.x;
    const int wave = tid >> 6;       // 0..3, owns u in [64*wave, 64*wave+64)
    const int lane = tid & 63;
    const int l15  = lane & 15;
    const int g    = lane >> 4;      // 0..3
    const int ubase = wave * 64;

    // ---- hoist first x-tile loads: in flight during the whole mu setup ----
    int rt = blockIdx.x;
    const float* xr0 = x + (size_t)(rt * 16 + l15) * 64 + 8 * g;
    floatx4 c0 = *(const floatx4*)(xr0);
    floatx4 c1 = *(const floatx4*)(xr0 + 4);
    floatx4 c2 = *(const floatx4*)(xr0 + 32);
    floatx4 c3 = *(const floatx4*)(xr0 + 36);

    // ---- mu fragments: loaded once per block, register-resident ----
    // lane holds mu[k = 32h + 8g + e][ubase + t*16 + l15]; identical lane
    // mapping serves as the MFMA *A* operand (row = l15 -> u, k = 8g+e).
    short8 bfrag[4][2];
    float  msqT[4][4];   // -0.5*|mu_u|^2 for u = t*16 + 4g + r  (epilogue layout)
    #pragma unroll
    for (int t = 0; t < 4; ++t) {
        const int u = ubase + t * 16 + l15;
        float sq = 0.f;
        #pragma unroll
        for (int h = 0; h < 2; ++h) {
            short8 bf;
            const int k0 = 32 * h + 8 * g;
            #pragma unroll
            for (int e = 0; e < 8; ++e) {
                float v = mu[(k0 + e) * 256 + u];
                sq += v * v;
                bf[e] = f2bf_rne(v);
            }
            bfrag[t][h] = bf;
        }
        sq += __shfl_xor(sq, 16);
        sq += __shfl_xor(sq, 32);          // all g-copies now hold |mu_{t16+l15}|^2
        #pragma unroll
        for (int r = 0; r < 4; ++r)        // remap to epilogue lane layout (once)
            msqT[t][r] = -0.5f * __shfl(sq, 4 * g + r);
    }

    // ---- 4 row-tiles per block, 2-deep pipelined x loads ----
    #pragma unroll
    for (int i = 0; i < TILES; ++i) {
        floatx4 n0, n1, n2, n3;
        if (i + 1 < TILES) {
            const float* xn = x + (size_t)((rt + GRIDB) * 16 + l15) * 64 + 8 * g;
            n0 = *(const floatx4*)(xn);
            n1 = *(const floatx4*)(xn + 4);
            n2 = *(const floatx4*)(xn + 32);
            n3 = *(const floatx4*)(xn + 36);
        }

        // x frag: lane holds x[b0 + l15][k = 32h + 8g + e]; identical lane
        // mapping serves as the MFMA *B* operand (k = 8g+e, col = l15 -> b).
        short8 a0, a1;
        float xsq = 0.f;
        #pragma unroll
        for (int e = 0; e < 4; ++e) {
            xsq += c0[e] * c0[e] + c1[e] * c1[e];
            xsq += c2[e] * c2[e] + c3[e] * c3[e];
            a0[e]     = f2bf_rne(c0[e]);
            a0[e + 4] = f2bf_rne(c1[e]);
            a1[e]     = f2bf_rne(c2[e]);
            a1[e + 4] = f2bf_rne(c3[e]);
        }
        xsq += __shfl_xor(xsq, 16);
        xsq += __shfl_xor(xsq, 32);        // lane holds |x_{b0+l15}|^2 -- its own row
        const float xh = -0.5f * xsq;

        const size_t orow = (size_t)(rt * 16 + l15) * 256 + ubase;
        #pragma unroll
        for (int t = 0; t < 4; ++t) {
            floatx4 acc = {0.f, 0.f, 0.f, 0.f};
            // swapped operands -> D = mu^T-tile * x-tile = C^T
            acc = __builtin_amdgcn_mfma_f32_16x16x32_bf16(bfrag[t][0], a0, acc, 0, 0, 0);
            acc = __builtin_amdgcn_mfma_f32_16x16x32_bf16(bfrag[t][1], a1, acc, 0, 0, 0);
            floatx4 v;
            #pragma unroll
            for (int r = 0; r < 4; ++r)
                v[r] = __expf(acc[r] + xh + msqT[t][r]);
            *(floatx4*)&out[orow + t * 16 + 4 * g] = v;   // 16B/lane, contiguous
        }

        if (i + 1 < TILES) {
            c0 = n0; c1 = n1; c2 = n2; c3 = n3;
            rt += GRIDB;
        }
    }
}

extern "C" void kernel_launch(void* const* d_in, const int* in_sizes, int n_in,
                              void* d_out, int out_size, void* d_ws, size_t ws_size,
                              hipStream_t stream) {
    const float* x  = (const float*)d_in[0];   // (65536, 64)
    const float* mu = (const float*)d_in[1];   // (64, 256)
    float* out = (float*)d_out;                // (65536, 256)
    hipLaunchKernelGGL(rbf_kernel, dim3(GRIDB), dim3(256), 0, stream, x, mu, out);
}